// Round 8
// baseline (180.507 us; speedup 1.0000x reference)
//
#include <hip/hip_runtime.h>
#include <hip/hip_bf16.h>

typedef __attribute__((ext_vector_type(8))) short short8;
typedef __attribute__((ext_vector_type(4))) float f32x4;
typedef unsigned short u16;
typedef unsigned int u32;

#define T_TOK 32768
#define CDIM  512
#define HEADS 8
#define HD    64
#define NSEQ  8192

#define AS1 __attribute__((address_space(1)))
#define AS3 __attribute__((address_space(3)))

__device__ __forceinline__ u16 f2bf(float f) {
  u32 u = __builtin_bit_cast(u32, f);
  u = u + 0x7fffu + ((u >> 16) & 1u);   // RNE
  return (u16)(u >> 16);
}
__device__ __forceinline__ float bf2f(u16 s) {
  return __builtin_bit_cast(float, ((u32)s) << 16);
}

// ---------------- K0a: x f32 -> bf16 (one-time) ----------------------------------------
__global__ __launch_bounds__(256) void k_convx(const float* __restrict__ x,
                                               u16* __restrict__ xb) {
  size_t i = (size_t)blockIdx.x * 256 + threadIdx.x;
  size_t stride = (size_t)gridDim.x * 256;
  size_t total = (size_t)T_TOK * 512 / 8;
  for (; i < total; i += stride) {
    float4 a = *reinterpret_cast<const float4*>(&x[i * 8]);
    float4 b = *reinterpret_cast<const float4*>(&x[i * 8 + 4]);
    ushort4 r0, r1;
    r0.x = f2bf(a.x); r0.y = f2bf(a.y); r0.z = f2bf(a.z); r0.w = f2bf(a.w);
    r1.x = f2bf(b.x); r1.y = f2bf(b.y); r1.z = f2bf(b.z); r1.w = f2bf(b.w);
    *reinterpret_cast<ushort4*>(&xb[i * 8])     = r0;
    *reinterpret_cast<ushort4*>(&xb[i * 8 + 4]) = r1;
  }
}

// ---------------- K0b: pack all 4 weight matrices to bf16, [2048][512] -----------------
__global__ void k_pack_w(const float* __restrict__ Wq, const float* __restrict__ Wk,
                         const float* __restrict__ Wv, const float* __restrict__ Wo,
                         u16* __restrict__ Wcat) {
  int idx = blockIdx.x * 256 + threadIdx.x;   // over 2048*512
  int c = idx & 511;
  int o2 = idx >> 9;
  const float* W = (o2 < 512) ? Wq : (o2 < 1024) ? Wk : (o2 < 1536) ? Wv : Wo;
  int o = o2 & 511;
  Wcat[idx] = f2bf(W[o * 512 + c]);
}

// ---------------- K1/K5: 256^2-tile 8-PHASE GEMM (m201 template port) ------------------
// MODE 0: A=xb[32768][512], B rows 0..1535 of Wcat, out=qkv bf16 stride 1536, elu+1 on q,k
// MODE 1: A=attn[32768][512], B rows 1536..2047, out=f32 stride 512, bias b0
// BM=BN=256, BK=64, 512 thr = 8 waves (2Mx4N), wave C = 128x64 (acc_a m0-3 / acc_b m4-7).
// LDS: kk-half arrays [dbuf][kk][256][32] (64B rows, linear DMA dest, no swizzle needed —
// read multiplicity = 8 lanes per 4-bank group, same as r3's measured-0-conflict layout).
// Per K-tile 4 phases: (kk0,mh0)(kk0,mh1)(kk1,mh0)(kk1,mh1); each phase:
//   {ds_read 4-8 x b128 | stage 1 half-tile (2x global_load_lds) | [vmcnt] | barrier |
//    setprio(1) 16xMFMA setprio(0) | barrier}
// Half-tile free/stage/consume chain (hand-verified): kk0 of buf d frees at end of phase 2
// of its tile; stages issue 4-6 phases before consumption; vmcnt(4) at phases 4/8 only.
// Accumulation order per acc element unchanged -> bit-identical output vs r6.
template<int MODE>
__global__ __launch_bounds__(512, 2) void k_gemm(const u16* __restrict__ Ag,
    const u16* __restrict__ Wcat,
    const float* __restrict__ b0, const float* __restrict__ b1, const float* __restrict__ b2,
    u16* __restrict__ obf, float* __restrict__ of32) {
  constexpr int NT = (MODE == 0) ? 6 : 2;         // 256-wide n-tiles
  constexpr int BROW = (MODE == 0) ? 0 : 1536;    // Wcat row offset
  constexpr int OSTRIDE = (MODE == 0) ? 1536 : 512;
  __shared__ u16 As[2][2][256][32];   // [dbuf][kk-half][row][k] = 64 KB
  __shared__ u16 Bs[2][2][256][32];   // 64 KB
  int bid = blockIdx.x;
  constexpr int GRID = (T_TOK / 256) * NT;
  constexpr int CHUNK = GRID / 8;                 // blocks per XCD
  int swz = (bid & 7) * CHUNK + (bid >> 3);       // bijective: GRID % 8 == 0
  int m0 = (swz / NT) * 256;
  int n0 = (swz % NT) * 256;
  int tid = threadIdx.x;
  int lane = tid & 63, w = tid >> 6;
  int wr = w >> 2, wc = w & 3;
  f32x4 acc_a[4][4], acc_b[4][4];
  _Pragma("unroll")
  for (int i = 0; i < 4; ++i)
    _Pragma("unroll")
    for (int j = 0; j < 4; ++j) { acc_a[i][j] = (f32x4)0.0f; acc_b[i][j] = (f32x4)0.0f; }

  const u16* Bg = Wcat + (size_t)BROW * 512;
  int l15 = lane & 15, lhi = lane >> 4;
  int grow = w * 16 + (lane >> 2);     // staging row within 128-row half (lane part)
  int gk   = (lane & 3) * 8;           // staging k-chunk (8 bf16 = 16 B)

// stage one A half-tile: [buf d][kk h] <- tile t's k-cols [t*64+h*32 .. +32), rows 0..255
#define SA(d, h, t)                                                                        \
  _Pragma("unroll") for (int j_ = 0; j_ < 2; ++j_)                                         \
    __builtin_amdgcn_global_load_lds(                                                      \
        (const AS1 void*)&Ag[(size_t)(m0 + j_ * 128 + grow) * 512 + (t) * 64 + (h) * 32 + gk], \
        (AS3 void*)&As[d][h][j_ * 128 + w * 16][0], 16, 0, 0);
#define SB(d, h, t)                                                                        \
  _Pragma("unroll") for (int j_ = 0; j_ < 2; ++j_)                                         \
    __builtin_amdgcn_global_load_lds(                                                      \
        (const AS1 void*)&Bg[(size_t)(n0 + j_ * 128 + grow) * 512 + (t) * 64 + (h) * 32 + gk], \
        (AS3 void*)&Bs[d][h][j_ * 128 + w * 16][0], 16, 0, 0);
#define VW(n) asm volatile("s_waitcnt vmcnt(" #n ")" ::: "memory");

// phase mh=0: load af (m0-3) + bfr, stage, barrier, 16 MFMA into acc_a, barrier
#define PH0(d, kk, ...) {                                                                  \
    _Pragma("unroll") for (int m = 0; m < 4; ++m)                                          \
      af[m] = *reinterpret_cast<const short8*>(&As[d][kk][wr * 128 + m * 16 + l15][lhi * 8]); \
    _Pragma("unroll") for (int n = 0; n < 4; ++n)                                          \
      bfr[n] = *reinterpret_cast<const short8*>(&Bs[d][kk][wc * 64 + n * 16 + l15][lhi * 8]); \
    __VA_ARGS__                                                                            \
    __builtin_amdgcn_s_barrier();                                                          \
    __builtin_amdgcn_s_setprio(1);                                                         \
    _Pragma("unroll") for (int m = 0; m < 4; ++m)                                          \
      _Pragma("unroll") for (int n = 0; n < 4; ++n)                                        \
        acc_a[m][n] = __builtin_amdgcn_mfma_f32_16x16x32_bf16(af[m], bfr[n], acc_a[m][n], 0, 0, 0); \
    __builtin_amdgcn_s_setprio(0);                                                         \
    __builtin_amdgcn_s_barrier(); }
// phase mh=1: load af (m4-7), reuse bfr, 16 MFMA into acc_b
#define PH1(d, kk, ...) {                                                                  \
    _Pragma("unroll") for (int m = 0; m < 4; ++m)                                          \
      af[m] = *reinterpret_cast<const short8*>(&As[d][kk][wr * 128 + 64 + m * 16 + l15][lhi * 8]); \
    __VA_ARGS__                                                                            \
    __builtin_amdgcn_s_barrier();                                                          \
    __builtin_amdgcn_s_setprio(1);                                                         \
    _Pragma("unroll") for (int m = 0; m < 4; ++m)                                          \
      _Pragma("unroll") for (int n = 0; n < 4; ++n)                                        \
        acc_b[m][n] = __builtin_amdgcn_mfma_f32_16x16x32_bf16(af[m], bfr[n], acc_b[m][n], 0, 0, 0); \
    __builtin_amdgcn_s_setprio(0);                                                         \
    __builtin_amdgcn_s_barrier(); }

  short8 af[4], bfr[4];
  // prologue: t0 all 4 halves + t1 kk0 halves (12 loads); confirm t0 (leave 4 in flight)
  SA(0, 0, 0) SB(0, 0, 0) SA(0, 1, 0) SB(0, 1, 0) SA(1, 0, 1) SB(1, 0, 1)
  VW(4)
  __builtin_amdgcn_s_barrier();
  // i=0: tiles 0(buf0), 1(buf1); stage t1-kk1, t2, t3-kk0
  PH0(0, 0, SA(1, 1, 1)) PH1(0, 0, SB(1, 1, 1))
  PH0(0, 1, SA(0, 0, 2)) PH1(0, 1, SB(0, 0, 2) VW(4))
  PH0(1, 0, SA(0, 1, 2)) PH1(1, 0, SB(0, 1, 2))
  PH0(1, 1, SA(1, 0, 3)) PH1(1, 1, SB(1, 0, 3) VW(4))
  // i=1: tiles 2,3; stage t3-kk1, t4, t5-kk0
  PH0(0, 0, SA(1, 1, 3)) PH1(0, 0, SB(1, 1, 3))
  PH0(0, 1, SA(0, 0, 4)) PH1(0, 1, SB(0, 0, 4) VW(4))
  PH0(1, 0, SA(0, 1, 4)) PH1(1, 0, SB(0, 1, 4))
  PH0(1, 1, SA(1, 0, 5)) PH1(1, 1, SB(1, 0, 5) VW(4))
  // i=2: tiles 4,5; stage t5-kk1, t6, t7-kk0
  PH0(0, 0, SA(1, 1, 5)) PH1(0, 0, SB(1, 1, 5))
  PH0(0, 1, SA(0, 0, 6)) PH1(0, 1, SB(0, 0, 6) VW(4))
  PH0(1, 0, SA(0, 1, 6)) PH1(1, 0, SB(0, 1, 6))
  PH0(1, 1, SA(1, 0, 7)) PH1(1, 1, SB(1, 0, 7) VW(4))
  // i=3 (tail): tiles 6,7; stage only t7-kk1; drain at P4
  PH0(0, 0, SA(1, 1, 7)) PH1(0, 0, SB(1, 1, 7))
  PH0(0, 1, )            PH1(0, 1, VW(0))
  PH0(1, 0, )            PH1(1, 0, )
  PH0(1, 1, )            PH1(1, 1, )
#undef SA
#undef SB
#undef VW
#undef PH0
#undef PH1

  _Pragma("unroll")
  for (int m = 0; m < 4; ++m) {
    _Pragma("unroll")
    for (int half = 0; half < 2; ++half) {
      int row = m0 + wr * 128 + half * 64 + m * 16 + lhi * 4;
      _Pragma("unroll")
      for (int n = 0; n < 4; ++n) {
        int col = n0 + wc * 64 + n * 16 + l15;
        float bias;
        if (MODE == 0)
          bias = (col < 512) ? b0[col] : (col < 1024) ? b1[col - 512] : b2[col - 1024];
        else
          bias = b0[col];
        _Pragma("unroll")
        for (int j = 0; j < 4; ++j) {
          float vv = (half == 0 ? acc_a[m][n][j] : acc_b[m][n][j]) + bias;
          if (MODE == 0) {
            if (col < 1024) vv = (vv > 0.0f) ? (vv + 1.0f) : __expf(vv);
            obf[(size_t)(row + j) * OSTRIDE + col] = f2bf(vv);
          } else {
            of32[(size_t)(row + j) * OSTRIDE + col] = vv;
          }
        }
      }
    }
  }
}

// ---------------- K2: per (head, K-split): partial kv[64][64] and ksum[64] -------------
// 16 splits of 512 tokens. Transposed LDS tiles with slot-XOR swizzle (pure-LDS, both
// sides): logical [d][t] lives at [d][t ^ 8*((d>>2)&3)] -> stores 4-way, reads ~2-way.
__global__ __launch_bounds__(256) void k_kvstats(const u16* __restrict__ qkv,
    float* __restrict__ kvp, float* __restrict__ ksp) {
  __shared__ u16 kt[64][32];     // transposed: [d][t'] (swizzled)
  __shared__ u16 vt[64][32];     // transposed: [e][t'] (swizzled)
  __shared__ float ks_red[4][64];
  int hh = blockIdx.x;           // 0..31  (b*8+h)
  int s  = blockIdx.y;           // 0..15
  int b = hh >> 3, h = hh & 7;
  int tid = threadIdx.x;
  int lane = tid & 63, w = tid >> 6;
  size_t tbase = (size_t)b * NSEQ + (size_t)s * 512;
  f32x4 acc[4];
  for (int n = 0; n < 4; ++n) acc[n] = (f32x4)0.0f;
  float ksum_loc = 0.0f;
  int kcol = 512 + h * 64;
  int vcol = 1024 + h * 64;
  int l15 = lane & 15;
  int rsw = 8 * (l15 >> 2);            // read-side XOR for rows 16-aligned

  for (int step = 0; step < 16; ++step) {
    size_t t0 = tbase + (size_t)step * 32;
    for (int jj = 0; jj < 4; ++jj) {
      int id = tid + 256 * jj;           // 0..1023
      int trow = (id >> 4) & 31;
      int dq = id & 15;
      int isv = id >> 9;                 // 0: k-tile, 1: v-tile
      ushort4 val = *reinterpret_cast<const ushort4*>(
          &qkv[(t0 + trow) * 1536 + (isv ? vcol : kcol) + dq * 4]);
      u16 (*dst)[32] = isv ? vt : kt;
      int colw = trow ^ (8 * (dq & 3)); // store-side XOR: (d>>2)&3 == dq&3
      dst[dq * 4 + 0][colw] = val.x;
      dst[dq * 4 + 1][colw] = val.y;
      dst[dq * 4 + 2][colw] = val.z;
      dst[dq * 4 + 3][colw] = val.w;
    }
    __syncthreads();
    {   // ksum over this 32-token tile (logical col g*8+i -> physical XOR)
      int d = tid & 63, g = tid >> 6;
      int gs = 8 * (g ^ ((d >> 2) & 3));
      float sl = 0;
      for (int i = 0; i < 8; ++i) sl += bf2f(kt[d][gs + i]);
      ksum_loc += sl;
    }
    int kb = 8 * (lane >> 4);
    short8 af = *reinterpret_cast<const short8*>(&kt[w * 16 + l15][kb ^ rsw]);
    for (int n = 0; n < 4; ++n) {
      short8 bfr = *reinterpret_cast<const short8*>(&vt[n * 16 + l15][kb ^ rsw]);
      acc[n] = __builtin_amdgcn_mfma_f32_16x16x32_bf16(af, bfr, acc[n], 0, 0, 0);
    }
    __syncthreads();
  }
  size_t pbase = ((size_t)hh * 16 + s) * 4096;
  for (int n = 0; n < 4; ++n) {
    int d = w * 16 + (lane >> 4) * 4;
    int e = n * 16 + (lane & 15);
    for (int j = 0; j < 4; ++j)
      kvp[pbase + (size_t)(d + j) * 64 + e] = acc[n][j];
  }
  ks_red[tid >> 6][tid & 63] = ksum_loc;
  __syncthreads();
  if (tid < 64) {
    float r = ks_red[0][tid] + ks_red[1][tid] + ks_red[2][tid] + ks_red[3][tid];
    ksp[((size_t)hh * 16 + s) * 64 + tid] = r;
  }
}

// ---------------- K3: reduce split partials -> kv^T bf16 ([hh][e][d]) + ksum f32 -------
__global__ void k_reduce(const float* __restrict__ kvp, const float* __restrict__ ksp,
                         u16* __restrict__ kvb, float* __restrict__ ksum) {
  int hh = blockIdx.x;
  int sl = blockIdx.y;                // 0..7
  int tid = threadIdx.x;
  for (int j = 0; j < 2; ++j) {
    int idx = sl * 512 + tid + 256 * j;     // d*64+e
    float a = 0;
    for (int s = 0; s < 16; ++s) a += kvp[((size_t)hh * 16 + s) * 4096 + idx];
    int d = idx >> 6, e = idx & 63;
    kvb[(size_t)hh * 4096 + e * 64 + d] = f2bf(a);   // store transposed for B-fragments
  }
  if (sl == 0 && tid < 64) {
    float a = 0;
    for (int s = 0; s < 16; ++s) a += ksp[((size_t)hh * 16 + s) * 64 + tid];
    ksum[hh * 64 + tid] = a;
  }
}

// ---------------- K4: attn[t][512] = (q @ kv) / (q . ksum + eps), bf16 -----------------
__global__ __launch_bounds__(256) void k_attn(const u16* __restrict__ qkv,
    const u16* __restrict__ kvb, const float* __restrict__ ksum,
    u16* __restrict__ attn) {
  __shared__ u16 qf[32][520];
  __shared__ float zl[32][8];
  __shared__ float kss[8][64];
  int tid = threadIdx.x;
  int lane = tid & 63, w = tid >> 6;
  size_t t0 = (size_t)blockIdx.x * 32;
  int b = (int)(t0 >> 13);
  for (int jj = 0; jj < 16; ++jj) {
    int id = tid + 256 * jj;          // 0..4095
    int row = id >> 7, cq = id & 127;
    *reinterpret_cast<ushort4*>(&qf[row][cq * 4]) =
        *reinterpret_cast<const ushort4*>(&qkv[(t0 + row) * 1536 + cq * 4]);
  }
  { int i = tid, i2 = tid + 256;       // stage 512 ksum floats
    kss[i >> 6][i & 63]   = ksum[b * 512 + i];
    kss[i2 >> 6][i2 & 63] = ksum[b * 512 + i2]; }
  __syncthreads();
  {   // z per (token, head) — vectorized short8 reads
    int tok = tid & 31, h = tid >> 5;
    float z = 0;
    for (int jq = 0; jq < 8; ++jq) {
      short8 qv = *reinterpret_cast<const short8*>(&qf[tok][h * 64 + jq * 8]);
      for (int e = 0; e < 8; ++e) z += bf2f((u16)qv[e]) * kss[h][jq * 8 + e];
    }
    zl[tok][h] = z + 1e-6f;
  }
  __syncthreads();
  for (int hi = 0; hi < 2; ++hi) {
    int h = w * 2 + hi;
    size_t kvoff = (size_t)(b * 8 + h) * 4096;
    f32x4 acc[2][4];
    for (int m = 0; m < 2; ++m) for (int n = 0; n < 4; ++n) acc[m][n] = (f32x4)0.0f;
    for (int kk = 0; kk < 2; ++kk) {
      int kb = kk * 32 + 8 * (lane >> 4);
      short8 af[2], bfr[4];
      for (int m = 0; m < 2; ++m)
        af[m] = *reinterpret_cast<const short8*>(&qf[m * 16 + (lane & 15)][h * 64 + kb]);
      for (int n = 0; n < 4; ++n)
        bfr[n] = *reinterpret_cast<const short8*>(&kvb[kvoff + (size_t)(n * 16 + (lane & 15)) * 64 + kb]);
      for (int m = 0; m < 2; ++m)
        for (int n = 0; n < 4; ++n)
          acc[m][n] = __builtin_amdgcn_mfma_f32_16x16x32_bf16(af[m], bfr[n], acc[m][n], 0, 0, 0);
    }
    for (int m = 0; m < 2; ++m) {
      int tokb = m * 16 + (lane >> 4) * 4;
      for (int n = 0; n < 4; ++n) {
        int e = n * 16 + (lane & 15);
        for (int j = 0; j < 4; ++j) {
          float vv = acc[m][n][j] / zl[tokb + j][h];
          attn[(t0 + tokb + j) * 512 + h * 64 + e] = f2bf(vv);
        }
      }
    }
  }
}

extern "C" void kernel_launch(void* const* d_in, const int* in_sizes, int n_in,
                              void* d_out, int out_size, void* d_ws, size_t ws_size,
                              hipStream_t stream) {
  const float* x  = (const float*)d_in[0];
  const float* Wq = (const float*)d_in[1];
  const float* bq = (const float*)d_in[2];
  const float* Wk = (const float*)d_in[3];
  const float* bk = (const float*)d_in[4];
  const float* Wv = (const float*)d_in[5];
  const float* bv = (const float*)d_in[6];
  const float* Wo = (const float*)d_in[7];
  const float* bo = (const float*)d_in[8];
  float* out = (float*)d_out;

  char* ws = (char*)d_ws;
  u16*   Wcat = (u16*)(ws + 0);                 //   2,097,152 B
  u16*   qkv  = (u16*)(ws + 2097152);           // 100,663,296 B
  // Region at 102,760,448 is time-shared (strict stream order):
  //   xb   (33.5 MB)  written by convx, read by gemm<0>
  //   kvp  ( 8.4 MB)  written by kvstats (after gemm<0>), read by reduce
  //   attn (33.5 MB)  written by k_attn (after reduce), read by gemm<1>
  u16*   xb   = (u16*)(ws + 102760448);
  float* kvp  = (float*)(ws + 102760448);
  u16*   attn = (u16*)(ws + 102760448);
  float* ksp  = (float*)(ws + 136314880);       //     131,072 B
  u16*   kvb  = (u16*)(ws + 136445952);         //     262,144 B
  float* ksum = (float*)(ws + 136708096);       //       8,192 B   (peak ~130.4 MiB)

  k_convx  <<<2048, 256, 0, stream>>>(x, xb);
  k_pack_w <<<4096, 256, 0, stream>>>(Wq, Wk, Wv, Wo, Wcat);
  k_gemm<0><<<768, 512, 0, stream>>>(xb, Wcat, bq, bk, bv, qkv, nullptr);
  k_kvstats<<<dim3(32, 16), 256, 0, stream>>>(qkv, kvp, ksp);
  k_reduce <<<dim3(32, 8), 256, 0, stream>>>(kvp, ksp, kvb, ksum);
  k_attn   <<<1024, 256, 0, stream>>>(qkv, kvb, ksum, attn);
  k_gemm<1><<<256, 512, 0, stream>>>(attn, Wcat, bo, nullptr, nullptr, nullptr, out);
}

// Round 9
// 180.035 us; speedup vs baseline: 1.0026x; 1.0026x over previous
//
#include <hip/hip_runtime.h>
#include <hip/hip_bf16.h>

typedef __attribute__((ext_vector_type(8))) short short8;
typedef __attribute__((ext_vector_type(4))) float f32x4;
typedef unsigned short u16;
typedef unsigned int u32;

#define T_TOK 32768
#define CDIM  512
#define HEADS 8
#define HD    64
#define NSEQ  8192

#define AS1 __attribute__((address_space(1)))
#define AS3 __attribute__((address_space(3)))

__device__ __forceinline__ u16 f2bf(float f) {
  u32 u = __builtin_bit_cast(u32, f);
  u = u + 0x7fffu + ((u >> 16) & 1u);   // RNE
  return (u16)(u >> 16);
}
__device__ __forceinline__ float bf2f(u16 s) {
  return __builtin_bit_cast(float, ((u32)s) << 16);
}

// ---------------- K0a: x f32 -> bf16 (one-time) ----------------------------------------
__global__ __launch_bounds__(256) void k_convx(const float* __restrict__ x,
                                               u16* __restrict__ xb) {
  size_t i = (size_t)blockIdx.x * 256 + threadIdx.x;
  size_t stride = (size_t)gridDim.x * 256;
  size_t total = (size_t)T_TOK * 512 / 8;
  for (; i < total; i += stride) {
    float4 a = *reinterpret_cast<const float4*>(&x[i * 8]);
    float4 b = *reinterpret_cast<const float4*>(&x[i * 8 + 4]);
    ushort4 r0, r1;
    r0.x = f2bf(a.x); r0.y = f2bf(a.y); r0.z = f2bf(a.z); r0.w = f2bf(a.w);
    r1.x = f2bf(b.x); r1.y = f2bf(b.y); r1.z = f2bf(b.z); r1.w = f2bf(b.w);
    *reinterpret_cast<ushort4*>(&xb[i * 8])     = r0;
    *reinterpret_cast<ushort4*>(&xb[i * 8 + 4]) = r1;
  }
}

// ---------------- K0b: pack all 4 weight matrices to bf16, [2048][512] -----------------
__global__ void k_pack_w(const float* __restrict__ Wq, const float* __restrict__ Wk,
                         const float* __restrict__ Wv, const float* __restrict__ Wo,
                         u16* __restrict__ Wcat) {
  int idx = blockIdx.x * 256 + threadIdx.x;   // over 2048*512
  int c = idx & 511;
  int o2 = idx >> 9;
  const float* W = (o2 < 512) ? Wq : (o2 < 1024) ? Wk : (o2 < 1536) ? Wv : Wo;
  int o = o2 & 511;
  Wcat[idx] = f2bf(W[o * 512 + c]);
}

// ---------------- K1/K5: 256^2-tile 8-PHASE GEMM (m201 template port) ------------------
// MODE 0: A=xb[32768][512], B rows 0..1535 of Wcat, out=qkv bf16 stride 1536, elu+1 on q,k
// MODE 1: A=attn[32768][512], B rows 1536..2047, out=f32 stride 512, bias b0
// BM=BN=256, BK=64, 512 thr = 8 waves (2Mx4N), wave C = 128x64 (acc_a m0-3 / acc_b m4-7).
// LDS: kk-half arrays [dbuf][kk][256][32] (64B rows, linear DMA dest, no swizzle needed —
// read multiplicity = 8 lanes per 4-bank group, same as r3's measured-0-conflict layout).
// Per K-tile 4 phases: (kk0,mh0)(kk0,mh1)(kk1,mh0)(kk1,mh1); each phase:
//   {ds_read 4-8 x b128 | stage 1 half-tile (2x global_load_lds) | [vmcnt] | barrier |
//    setprio(1) 16xMFMA setprio(0) | barrier}
// Half-tile free/stage/consume chain (hand-verified): kk0 of buf d frees at end of phase 2
// of its tile; stages issue 4-6 phases before consumption; vmcnt(4) at phases 4/8 only.
// Accumulation order per acc element unchanged -> bit-identical output vs r6.
template<int MODE>
__global__ __launch_bounds__(512, 2) void k_gemm(const u16* __restrict__ Ag,
    const u16* __restrict__ Wcat,
    const float* __restrict__ b0, const float* __restrict__ b1, const float* __restrict__ b2,
    u16* __restrict__ obf, float* __restrict__ of32) {
  constexpr int NT = (MODE == 0) ? 6 : 2;         // 256-wide n-tiles
  constexpr int BROW = (MODE == 0) ? 0 : 1536;    // Wcat row offset
  constexpr int OSTRIDE = (MODE == 0) ? 1536 : 512;
  __shared__ u16 As[2][2][256][32];   // [dbuf][kk-half][row][k] = 64 KB
  __shared__ u16 Bs[2][2][256][32];   // 64 KB
  int bid = blockIdx.x;
  constexpr int GRID = (T_TOK / 256) * NT;
  constexpr int CHUNK = GRID / 8;                 // blocks per XCD
  int swz = (bid & 7) * CHUNK + (bid >> 3);       // bijective: GRID % 8 == 0
  int m0 = (swz / NT) * 256;
  int n0 = (swz % NT) * 256;
  int tid = threadIdx.x;
  int lane = tid & 63, w = tid >> 6;
  int wr = w >> 2, wc = w & 3;
  f32x4 acc_a[4][4], acc_b[4][4];
  _Pragma("unroll")
  for (int i = 0; i < 4; ++i)
    _Pragma("unroll")
    for (int j = 0; j < 4; ++j) { acc_a[i][j] = (f32x4)0.0f; acc_b[i][j] = (f32x4)0.0f; }

  const u16* Bg = Wcat + (size_t)BROW * 512;
  int l15 = lane & 15, lhi = lane >> 4;
  int grow = w * 16 + (lane >> 2);     // staging row within 128-row half (lane part)
  int gk   = (lane & 3) * 8;           // staging k-chunk (8 bf16 = 16 B)

// stage one A half-tile: [buf d][kk h] <- tile t's k-cols [t*64+h*32 .. +32), rows 0..255
#define SA(d, h, t)                                                                        \
  _Pragma("unroll") for (int j_ = 0; j_ < 2; ++j_)                                         \
    __builtin_amdgcn_global_load_lds(                                                      \
        (const AS1 void*)&Ag[(size_t)(m0 + j_ * 128 + grow) * 512 + (t) * 64 + (h) * 32 + gk], \
        (AS3 void*)&As[d][h][j_ * 128 + w * 16][0], 16, 0, 0);
#define SB(d, h, t)                                                                        \
  _Pragma("unroll") for (int j_ = 0; j_ < 2; ++j_)                                         \
    __builtin_amdgcn_global_load_lds(                                                      \
        (const AS1 void*)&Bg[(size_t)(n0 + j_ * 128 + grow) * 512 + (t) * 64 + (h) * 32 + gk], \
        (AS3 void*)&Bs[d][h][j_ * 128 + w * 16][0], 16, 0, 0);
#define VW(n) asm volatile("s_waitcnt vmcnt(" #n ")" ::: "memory");

// phase mh=0: load af (m0-3) + bfr, stage, barrier, 16 MFMA into acc_a, barrier
#define PH0(d, kk, ...) {                                                                  \
    _Pragma("unroll") for (int m = 0; m < 4; ++m)                                          \
      af[m] = *reinterpret_cast<const short8*>(&As[d][kk][wr * 128 + m * 16 + l15][lhi * 8]); \
    _Pragma("unroll") for (int n = 0; n < 4; ++n)                                          \
      bfr[n] = *reinterpret_cast<const short8*>(&Bs[d][kk][wc * 64 + n * 16 + l15][lhi * 8]); \
    __VA_ARGS__                                                                            \
    __builtin_amdgcn_s_barrier();                                                          \
    __builtin_amdgcn_s_setprio(1);                                                         \
    _Pragma("unroll") for (int m = 0; m < 4; ++m)                                          \
      _Pragma("unroll") for (int n = 0; n < 4; ++n)                                        \
        acc_a[m][n] = __builtin_amdgcn_mfma_f32_16x16x32_bf16(af[m], bfr[n], acc_a[m][n], 0, 0, 0); \
    __builtin_amdgcn_s_setprio(0);                                                         \
    __builtin_amdgcn_s_barrier(); }
// phase mh=1: load af (m4-7), reuse bfr, 16 MFMA into acc_b
#define PH1(d, kk, ...) {                                                                  \
    _Pragma("unroll") for (int m = 0; m < 4; ++m)                                          \
      af[m] = *reinterpret_cast<const short8*>(&As[d][kk][wr * 128 + 64 + m * 16 + l15][lhi * 8]); \
    __VA_ARGS__                                                                            \
    __builtin_amdgcn_s_barrier();                                                          \
    __builtin_amdgcn_s_setprio(1);                                                         \
    _Pragma("unroll") for (int m = 0; m < 4; ++m)                                          \
      _Pragma("unroll") for (int n = 0; n < 4; ++n)                                        \
        acc_b[m][n] = __builtin_amdgcn_mfma_f32_16x16x32_bf16(af[m], bfr[n], acc_b[m][n], 0, 0, 0); \
    __builtin_amdgcn_s_setprio(0);                                                         \
    __builtin_amdgcn_s_barrier(); }

  short8 af[4], bfr[4];
  // prologue: t0 all 4 halves + t1 kk0 halves (12 loads); confirm t0 (leave 4 in flight)
  SA(0, 0, 0) SB(0, 0, 0) SA(0, 1, 0) SB(0, 1, 0) SA(1, 0, 1) SB(1, 0, 1)
  VW(4)
  __builtin_amdgcn_s_barrier();
  // i=0: tiles 0(buf0), 1(buf1); stage t1-kk1, t2, t3-kk0
  PH0(0, 0, SA(1, 1, 1)) PH1(0, 0, SB(1, 1, 1))
  PH0(0, 1, SA(0, 0, 2)) PH1(0, 1, SB(0, 0, 2) VW(4))
  PH0(1, 0, SA(0, 1, 2)) PH1(1, 0, SB(0, 1, 2))
  PH0(1, 1, SA(1, 0, 3)) PH1(1, 1, SB(1, 0, 3) VW(4))
  // i=1: tiles 2,3; stage t3-kk1, t4, t5-kk0
  PH0(0, 0, SA(1, 1, 3)) PH1(0, 0, SB(1, 1, 3))
  PH0(0, 1, SA(0, 0, 4)) PH1(0, 1, SB(0, 0, 4) VW(4))
  PH0(1, 0, SA(0, 1, 4)) PH1(1, 0, SB(0, 1, 4))
  PH0(1, 1, SA(1, 0, 5)) PH1(1, 1, SB(1, 0, 5) VW(4))
  // i=2: tiles 4,5; stage t5-kk1, t6, t7-kk0
  PH0(0, 0, SA(1, 1, 5)) PH1(0, 0, SB(1, 1, 5))
  PH0(0, 1, SA(0, 0, 6)) PH1(0, 1, SB(0, 0, 6) VW(4))
  PH0(1, 0, SA(0, 1, 6)) PH1(1, 0, SB(0, 1, 6))
  PH0(1, 1, SA(1, 0, 7)) PH1(1, 1, SB(1, 0, 7) VW(4))
  // i=3 (tail): tiles 6,7; stage only t7-kk1; drain at P4
  PH0(0, 0, SA(1, 1, 7)) PH1(0, 0, SB(1, 1, 7))
  PH0(0, 1, )            PH1(0, 1, VW(0))
  PH0(1, 0, )            PH1(1, 0, )
  PH0(1, 1, )            PH1(1, 1, )
#undef SA
#undef SB
#undef VW
#undef PH0
#undef PH1

  _Pragma("unroll")
  for (int m = 0; m < 4; ++m) {
    _Pragma("unroll")
    for (int half = 0; half < 2; ++half) {
      int row = m0 + wr * 128 + half * 64 + m * 16 + lhi * 4;
      _Pragma("unroll")
      for (int n = 0; n < 4; ++n) {
        int col = n0 + wc * 64 + n * 16 + l15;
        float bias;
        if (MODE == 0)
          bias = (col < 512) ? b0[col] : (col < 1024) ? b1[col - 512] : b2[col - 1024];
        else
          bias = b0[col];
        _Pragma("unroll")
        for (int j = 0; j < 4; ++j) {
          float vv = (half == 0 ? acc_a[m][n][j] : acc_b[m][n][j]) + bias;
          if (MODE == 0) {
            if (col < 1024) vv = (vv > 0.0f) ? (vv + 1.0f) : __expf(vv);
            obf[(size_t)(row + j) * OSTRIDE + col] = f2bf(vv);
          } else {
            of32[(size_t)(row + j) * OSTRIDE + col] = vv;
          }
        }
      }
    }
  }
}

// ---------------- K2: per (head, K-split): partial kv[64][64] and ksum[64] -------------
// 16 splits of 512 tokens. Transposed LDS tiles with slot-XOR swizzle (pure-LDS, both
// sides): logical [d][t] lives at [d][t ^ 8*((d>>2)&3)] -> stores 4-way, reads ~2-way.
__global__ __launch_bounds__(256) void k_kvstats(const u16* __restrict__ qkv,
    float* __restrict__ kvp, float* __restrict__ ksp) {
  __shared__ u16 kt[64][32];     // transposed: [d][t'] (swizzled)
  __shared__ u16 vt[64][32];     // transposed: [e][t'] (swizzled)
  __shared__ float ks_red[4][64];
  int hh = blockIdx.x;           // 0..31  (b*8+h)
  int s  = blockIdx.y;           // 0..15
  int b = hh >> 3, h = hh & 7;
  int tid = threadIdx.x;
  int lane = tid & 63, w = tid >> 6;
  size_t tbase = (size_t)b * NSEQ + (size_t)s * 512;
  f32x4 acc[4];
  for (int n = 0; n < 4; ++n) acc[n] = (f32x4)0.0f;
  float ksum_loc = 0.0f;
  int kcol = 512 + h * 64;
  int vcol = 1024 + h * 64;
  int l15 = lane & 15;
  int rsw = 8 * (l15 >> 2);            // read-side XOR for rows 16-aligned

  for (int step = 0; step < 16; ++step) {
    size_t t0 = tbase + (size_t)step * 32;
    for (int jj = 0; jj < 4; ++jj) {
      int id = tid + 256 * jj;           // 0..1023
      int trow = (id >> 4) & 31;
      int dq = id & 15;
      int isv = id >> 9;                 // 0: k-tile, 1: v-tile
      ushort4 val = *reinterpret_cast<const ushort4*>(
          &qkv[(t0 + trow) * 1536 + (isv ? vcol : kcol) + dq * 4]);
      u16 (*dst)[32] = isv ? vt : kt;
      int colw = trow ^ (8 * (dq & 3)); // store-side XOR: (d>>2)&3 == dq&3
      dst[dq * 4 + 0][colw] = val.x;
      dst[dq * 4 + 1][colw] = val.y;
      dst[dq * 4 + 2][colw] = val.z;
      dst[dq * 4 + 3][colw] = val.w;
    }
    __syncthreads();
    {   // ksum over this 32-token tile (logical col g*8+i -> physical XOR)
      int d = tid & 63, g = tid >> 6;
      int gs = 8 * (g ^ ((d >> 2) & 3));
      float sl = 0;
      for (int i = 0; i < 8; ++i) sl += bf2f(kt[d][gs + i]);
      ksum_loc += sl;
    }
    int kb = 8 * (lane >> 4);
    short8 af = *reinterpret_cast<const short8*>(&kt[w * 16 + l15][kb ^ rsw]);
    for (int n = 0; n < 4; ++n) {
      short8 bfr = *reinterpret_cast<const short8*>(&vt[n * 16 + l15][kb ^ rsw]);
      acc[n] = __builtin_amdgcn_mfma_f32_16x16x32_bf16(af, bfr, acc[n], 0, 0, 0);
    }
    __syncthreads();
  }
  size_t pbase = ((size_t)hh * 16 + s) * 4096;
  for (int n = 0; n < 4; ++n) {
    int d = w * 16 + (lane >> 4) * 4;
    int e = n * 16 + (lane & 15);
    for (int j = 0; j < 4; ++j)
      kvp[pbase + (size_t)(d + j) * 64 + e] = acc[n][j];
  }
  ks_red[tid >> 6][tid & 63] = ksum_loc;
  __syncthreads();
  if (tid < 64) {
    float r = ks_red[0][tid] + ks_red[1][tid] + ks_red[2][tid] + ks_red[3][tid];
    ksp[((size_t)hh * 16 + s) * 64 + tid] = r;
  }
}

// ---------------- K3: reduce split partials -> kv^T bf16 ([hh][e][d]) + ksum f32 -------
__global__ void k_reduce(const float* __restrict__ kvp, const float* __restrict__ ksp,
                         u16* __restrict__ kvb, float* __restrict__ ksum) {
  int hh = blockIdx.x;
  int sl = blockIdx.y;                // 0..7
  int tid = threadIdx.x;
  for (int j = 0; j < 2; ++j) {
    int idx = sl * 512 + tid + 256 * j;     // d*64+e
    float a = 0;
    for (int s = 0; s < 16; ++s) a += kvp[((size_t)hh * 16 + s) * 4096 + idx];
    int d = idx >> 6, e = idx & 63;
    kvb[(size_t)hh * 4096 + e * 64 + d] = f2bf(a);   // store transposed for B-fragments
  }
  if (sl == 0 && tid < 64) {
    float a = 0;
    for (int s = 0; s < 16; ++s) a += ksp[((size_t)hh * 16 + s) * 64 + tid];
    ksum[hh * 64 + tid] = a;
  }
}

// ---------------- K4: attn[t][512] = (q @ kv) / (q . ksum + eps), bf16 -----------------
__global__ __launch_bounds__(256) void k_attn(const u16* __restrict__ qkv,
    const u16* __restrict__ kvb, const float* __restrict__ ksum,
    u16* __restrict__ attn) {
  __shared__ u16 qf[32][520];
  __shared__ float zl[32][8];
  __shared__ float kss[8][64];
  int tid = threadIdx.x;
  int lane = tid & 63, w = tid >> 6;
  size_t t0 = (size_t)blockIdx.x * 32;
  int b = (int)(t0 >> 13);
  for (int jj = 0; jj < 16; ++jj) {
    int id = tid + 256 * jj;          // 0..4095
    int row = id >> 7, cq = id & 127;
    *reinterpret_cast<ushort4*>(&qf[row][cq * 4]) =
        *reinterpret_cast<const ushort4*>(&qkv[(t0 + row) * 1536 + cq * 4]);
  }
  { int i = tid, i2 = tid + 256;       // stage 512 ksum floats
    kss[i >> 6][i & 63]   = ksum[b * 512 + i];
    kss[i2 >> 6][i2 & 63] = ksum[b * 512 + i2]; }
  __syncthreads();
  {   // z per (token, head) — vectorized short8 reads
    int tok = tid & 31, h = tid >> 5;
    float z = 0;
    for (int jq = 0; jq < 8; ++jq) {
      short8 qv = *reinterpret_cast<const short8*>(&qf[tok][h * 64 + jq * 8]);
      for (int e = 0; e < 8; ++e) z += bf2f((u16)qv[e]) * kss[h][jq * 8 + e];
    }
    zl[tok][h] = z + 1e-6f;
  }
  __syncthreads();
  for (int hi = 0; hi < 2; ++hi) {
    int h = w * 2 + hi;
    size_t kvoff = (size_t)(b * 8 + h) * 4096;
    f32x4 acc[2][4];
    for (int m = 0; m < 2; ++m) for (int n = 0; n < 4; ++n) acc[m][n] = (f32x4)0.0f;
    for (int kk = 0; kk < 2; ++kk) {
      int kb = kk * 32 + 8 * (lane >> 4);
      short8 af[2], bfr[4];
      for (int m = 0; m < 2; ++m)
        af[m] = *reinterpret_cast<const short8*>(&qf[m * 16 + (lane & 15)][h * 64 + kb]);
      for (int n = 0; n < 4; ++n)
        bfr[n] = *reinterpret_cast<const short8*>(&kvb[kvoff + (size_t)(n * 16 + (lane & 15)) * 64 + kb]);
      for (int m = 0; m < 2; ++m)
        for (int n = 0; n < 4; ++n)
          acc[m][n] = __builtin_amdgcn_mfma_f32_16x16x32_bf16(af[m], bfr[n], acc[m][n], 0, 0, 0);
    }
    for (int m = 0; m < 2; ++m) {
      int tokb = m * 16 + (lane >> 4) * 4;
      for (int n = 0; n < 4; ++n) {
        int e = n * 16 + (lane & 15);
        for (int j = 0; j < 4; ++j) {
          float vv = acc[m][n][j] / zl[tokb + j][h];
          attn[(t0 + tokb + j) * 512 + h * 64 + e] = f2bf(vv);
        }
      }
    }
  }
}

extern "C" void kernel_launch(void* const* d_in, const int* in_sizes, int n_in,
                              void* d_out, int out_size, void* d_ws, size_t ws_size,
                              hipStream_t stream) {
  const float* x  = (const float*)d_in[0];
  const float* Wq = (const float*)d_in[1];
  const float* bq = (const float*)d_in[2];
  const float* Wk = (const float*)d_in[3];
  const float* bk = (const float*)d_in[4];
  const float* Wv = (const float*)d_in[5];
  const float* bv = (const float*)d_in[6];
  const float* Wo = (const float*)d_in[7];
  const float* bo = (const float*)d_in[8];
  float* out = (float*)d_out;

  char* ws = (char*)d_ws;
  u16*   Wcat = (u16*)(ws + 0);                 //   2,097,152 B
  u16*   qkv  = (u16*)(ws + 2097152);           // 100,663,296 B
  // Region at 102,760,448 is time-shared (strict stream order):
  //   xb   (33.5 MB)  written by convx, read by gemm<0>
  //   kvp  ( 8.4 MB)  written by kvstats (after gemm<0>), read by reduce
  //   attn (33.5 MB)  written by k_attn (after reduce), read by gemm<1>
  u16*   xb   = (u16*)(ws + 102760448);
  float* kvp  = (float*)(ws + 102760448);
  u16*   attn = (u16*)(ws + 102760448);
  float* ksp  = (float*)(ws + 136314880);       //     131,072 B
  u16*   kvb  = (u16*)(ws + 136445952);         //     262,144 B
  float* ksum = (float*)(ws + 136708096);       //       8,192 B   (peak ~130.4 MiB)

  k_convx  <<<2048, 256, 0, stream>>>(x, xb);
  k_pack_w <<<4096, 256, 0, stream>>>(Wq, Wk, Wv, Wo, Wcat);
  k_gemm<0><<<768, 512, 0, stream>>>(xb, Wcat, bq, bk, bv, qkv, nullptr);
  k_kvstats<<<dim3(32, 16), 256, 0, stream>>>(qkv, kvp, ksp);
  k_reduce <<<dim3(32, 8), 256, 0, stream>>>(kvp, ksp, kvb, ksum);
  k_attn   <<<1024, 256, 0, stream>>>(qkv, kvb, ksum, attn);
  k_gemm<1><<<256, 512, 0, stream>>>(attn, Wcat, bo, nullptr, nullptr, nullptr, out);
}